// Round 1
// baseline (282.605 us; speedup 1.0000x reference)
//
#include <hip/hip_runtime.h>
#include <hip/hip_bf16.h>

typedef unsigned short u16;
typedef unsigned int u32;

#define AS1 __attribute__((address_space(1)))
#define AS3 __attribute__((address_space(3)))

typedef __attribute__((ext_vector_type(8))) __bf16 bf16x8;
typedef __attribute__((ext_vector_type(4))) float f32x4;
typedef __attribute__((ext_vector_type(8))) u16 u16x8;

static __device__ __forceinline__ u16 f2bf(float f) {
    u32 x = __builtin_bit_cast(u32, f);
    u32 r = (x + 0x7fffu + ((x >> 16) & 1u)) >> 16;
    return (u16)r;
}
static __device__ __forceinline__ float bf2f(u16 u) {
    u32 x = ((u32)u) << 16;
    return __builtin_bit_cast(float, x);
}
static __device__ __forceinline__ void gload_lds16(const void* g, void* l) {
    __builtin_amdgcn_global_load_lds((const AS1 u32*)g, (AS3 u32*)l, 16, 0, 0);
}

// ---------------- cast X (fp32 -> bf16), 8 elems/thread ----------------
__global__ __launch_bounds__(256) void k_cast_bf16(const float* __restrict__ in,
                                                   u16* __restrict__ out, int n8) {
    int i = blockIdx.x * 256 + threadIdx.x;
    if (i >= n8) return;
    typedef __attribute__((ext_vector_type(4))) float fx4;
    const fx4* p = (const fx4*)in;
    fx4 a = p[2 * i], b = p[2 * i + 1];
    u16x8 o;
    o[0] = f2bf(a[0]); o[1] = f2bf(a[1]); o[2] = f2bf(a[2]); o[3] = f2bf(a[3]);
    o[4] = f2bf(b[0]); o[5] = f2bf(b[1]); o[6] = f2bf(b[2]); o[7] = f2bf(b[3]);
    *(u16x8*)(out + (size_t)i * 8) = o;
}

// ------------- transpose + cast W: [K,N] fp32 -> [N,K] bf16 -------------
__global__ __launch_bounds__(256) void k_wtrans(const float* __restrict__ W,
                                                u16* __restrict__ Wt, int K_, int N_) {
    __shared__ u16 T[64][65];
    int nt = blockIdx.x, kt = blockIdx.y;
    int t = threadIdx.x, c = t & 63, r0 = t >> 6;
#pragma unroll
    for (int i = 0; i < 16; i++) {
        int k = r0 + i * 4;
        T[k][c] = f2bf(W[(size_t)(kt * 64 + k) * N_ + nt * 64 + c]);
    }
    __syncthreads();
#pragma unroll
    for (int i = 0; i < 16; i++) {
        int nn = r0 + i * 4;
        Wt[(size_t)(nt * 64 + nn) * K_ + kt * 64 + c] = T[c][nn];
    }
}

// ---------------- bf16 MFMA GEMM: A[M,K] x Bt[N,K]^T ----------------
// EPI=0: outf[M,N] fp32 + bias.  EPI=1: scatter to Q/K/V bf16 [B,H,S,dh] + bias.
template <int EPI>
__global__ __launch_bounds__(256, 2) void k_gemm(
    const u16* __restrict__ A, const u16* __restrict__ Bt,
    const float* __restrict__ bias, float* __restrict__ outf,
    u16* __restrict__ Qb, u16* __restrict__ Kb, u16* __restrict__ Vb,
    int Msz, int Nsz, int Ksz) {
    __shared__ u16 Al[128 * 64];
    __shared__ u16 Bl[128 * 64];
    int tid = threadIdx.x;
    int m0 = blockIdx.x * 128, n0 = blockIdx.y * 128;
    int w = tid >> 6, lane = tid & 63, l15 = lane & 15, lg = lane >> 4;
    int wr = (w >> 1) * 64, wc = (w & 1) * 64;
    f32x4 acc[4][4] = {};

    for (int k0 = 0; k0 < Ksz; k0 += 64) {
#pragma unroll
        for (int i = 0; i < 4; i++) {
            int c = i * 256 + tid;
            gload_lds16(A + (size_t)(m0 + (c >> 3)) * Ksz + k0 + (c & 7) * 8,
                        &Al[(c & ~63) * 8]);
        }
#pragma unroll
        for (int i = 0; i < 4; i++) {
            int c = i * 256 + tid;
            gload_lds16(Bt + (size_t)(n0 + (c >> 3)) * Ksz + k0 + (c & 7) * 8,
                        &Bl[(c & ~63) * 8]);
        }
        __syncthreads();
#pragma unroll
        for (int kk = 0; kk < 2; kk++) {
            bf16x8 af[4], bfr[4];
#pragma unroll
            for (int m = 0; m < 4; m++)
                af[m] = *(const bf16x8*)&Al[(wr + m * 16 + l15) * 64 + kk * 32 + lg * 8];
#pragma unroll
            for (int n = 0; n < 4; n++)
                bfr[n] = *(const bf16x8*)&Bl[(wc + n * 16 + l15) * 64 + kk * 32 + lg * 8];
#pragma unroll
            for (int m = 0; m < 4; m++)
#pragma unroll
                for (int n = 0; n < 4; n++)
                    acc[m][n] = __builtin_amdgcn_mfma_f32_16x16x32_bf16(af[m], bfr[n], acc[m][n], 0, 0, 0);
        }
        __syncthreads();
    }

    if (EPI == 0) {
#pragma unroll
        for (int n = 0; n < 4; n++) {
            int gn = n0 + wc + n * 16 + l15;
            float bv = bias[gn];
#pragma unroll
            for (int m = 0; m < 4; m++) {
                int gmb = m0 + wr + m * 16 + lg * 4;
#pragma unroll
                for (int r = 0; r < 4; r++)
                    outf[(size_t)(gmb + r) * Nsz + gn] = acc[m][n][r] + bv;
            }
        }
    } else {
#pragma unroll
        for (int n = 0; n < 4; n++) {
            int gn = n0 + wc + n * 16 + l15;
            float bv = bias[gn];
            int which = gn >> 10, d = gn & 1023, h = d >> 6, dd = d & 63;
            u16* dst = which == 0 ? Qb : (which == 1 ? Kb : Vb);
#pragma unroll
            for (int m = 0; m < 4; m++) {
                int gmb = m0 + wr + m * 16 + lg * 4;
#pragma unroll
                for (int r = 0; r < 4; r++) {
                    int gm = gmb + r;
                    int b = gm >> 10, s = gm & 1023;
                    dst[((size_t)(b * 16 + h) * 1024 + s) * 64 + dd] = f2bf(acc[m][n][r] + bv);
                }
            }
        }
    }
}

// ---------------- V transpose: [bh][S][64] -> [bh][64][S] ----------------
__global__ __launch_bounds__(256) void k_vtrans(const u16* __restrict__ Vb,
                                                u16* __restrict__ Vt) {
    __shared__ u16 T[64][65];
    int st = blockIdx.x, bh = blockIdx.y;
    int t = threadIdx.x, c = t & 63, r0 = t >> 6;
    const u16* Vh = Vb + (size_t)bh * 65536;
    u16* Vth = Vt + (size_t)bh * 65536;
#pragma unroll
    for (int i = 0; i < 16; i++) {
        int s = r0 + i * 4;
        T[s][c] = Vh[(size_t)(st * 64 + s) * 64 + c];
    }
    __syncthreads();
#pragma unroll
    for (int i = 0; i < 16; i++) {
        int d = r0 + i * 4;
        Vth[(size_t)d * 1024 + st * 64 + c] = T[c][d];
    }
}

// ---------------- vsum: per (bh,d) sum over s of V ----------------
__global__ __launch_bounds__(256) void k_vsum(const u16* __restrict__ Vb,
                                              float* __restrict__ vsum) {
    __shared__ float red[256];
    int bh = blockIdx.x, t = threadIdx.x;
    int d = t & 63, sr = t >> 6;
    const u16* Vh = Vb + (size_t)bh * 65536;
    float a = 0.f;
    for (int s = sr; s < 1024; s += 4) a += bf2f(Vh[(size_t)s * 64 + d]);
    red[t] = a;
    __syncthreads();
    if (t < 64) vsum[bh * 64 + t] = red[t] + red[t + 64] + red[t + 128] + red[t + 192];
}

// ---------------- attention: relu-softmax flash, bf16 MFMA ----------------
__global__ __launch_bounds__(256) void k_attn(const u16* __restrict__ Qb,
                                              const u16* __restrict__ Kb,
                                              const u16* __restrict__ Vt,
                                              const float* __restrict__ vsum,
                                              u16* __restrict__ ctx) {
    __shared__ u16 Pl[4 * 2048];
    int qt = blockIdx.x, bh = blockIdx.y;
    int tid = threadIdx.x, w = tid >> 6, lane = tid & 63, l15 = lane & 15, lg = lane >> 4;
    const u16* Qh = Qb + (size_t)bh * 65536;
    const u16* Kh = Kb + (size_t)bh * 65536;
    const u16* Vh = Vt + (size_t)bh * 65536;
    int qbase = qt * 128 + w * 32;
    u16* Pw = &Pl[w * 2048];

    bf16x8 qf[2][2];
#pragma unroll
    for (int qi = 0; qi < 2; qi++)
#pragma unroll
        for (int kk = 0; kk < 2; kk++)
            qf[qi][kk] = *(const bf16x8*)(Qh + (size_t)(qbase + qi * 16 + l15) * 64 + kk * 32 + lg * 8);

    f32x4 ctxa[2][4] = {};
    float rs[2][4] = {};
    int nkb = (qbase + 95) >> 6;
    for (int kb = 0; kb < nkb; kb++) {
        f32x4 sc[2][4] = {};
#pragma unroll
        for (int kk = 0; kk < 2; kk++) {
            bf16x8 kf[4];
#pragma unroll
            for (int n = 0; n < 4; n++)
                kf[n] = *(const bf16x8*)(Kh + (size_t)(kb * 64 + n * 16 + l15) * 64 + kk * 32 + lg * 8);
#pragma unroll
            for (int qi = 0; qi < 2; qi++)
#pragma unroll
                for (int n = 0; n < 4; n++)
                    sc[qi][n] = __builtin_amdgcn_mfma_f32_16x16x32_bf16(qf[qi][kk], kf[n], sc[qi][n], 0, 0, 0);
        }
#pragma unroll
        for (int qi = 0; qi < 2; qi++)
#pragma unroll
            for (int n = 0; n < 4; n++)
#pragma unroll
                for (int r = 0; r < 4; r++) {
                    int qrow = qi * 16 + lg * 4 + r;
                    int q = qbase + qrow;
                    int k = kb * 64 + n * 16 + l15;
                    float p = sc[qi][n][r] * 0.125f;
                    p = (k <= q) ? fmaxf(p, 0.f) : 0.f;
                    rs[qi][r] += p;
                    int byte = qrow * 128 + (n * 16 + l15) * 2;
                    byte ^= (qrow & 7) << 4;  // XOR-swizzle (G4)
                    Pw[byte >> 1] = f2bf(p);
                }
#pragma unroll
        for (int kk = 0; kk < 2; kk++) {
            bf16x8 pf[2], vf[4];
#pragma unroll
            for (int qi = 0; qi < 2; qi++) {
                int row = qi * 16 + l15;
                int byte = row * 128 + (kk * 32 + lg * 8) * 2;
                byte ^= (row & 7) << 4;
                pf[qi] = *(const bf16x8*)&Pw[byte >> 1];
            }
#pragma unroll
            for (int n = 0; n < 4; n++)
                vf[n] = *(const bf16x8*)(Vh + (size_t)(n * 16 + l15) * 1024 + kb * 64 + kk * 32 + lg * 8);
#pragma unroll
            for (int qi = 0; qi < 2; qi++)
#pragma unroll
                for (int n = 0; n < 4; n++)
                    ctxa[qi][n] = __builtin_amdgcn_mfma_f32_16x16x32_bf16(pf[qi], vf[n], ctxa[qi][n], 0, 0, 0);
        }
    }
#pragma unroll
    for (int qi = 0; qi < 2; qi++)
#pragma unroll
        for (int r = 0; r < 4; r++) {
            float t = rs[qi][r];
            t += __shfl_xor(t, 1); t += __shfl_xor(t, 2);
            t += __shfl_xor(t, 4); t += __shfl_xor(t, 8);
            rs[qi][r] = t;
        }
    const float EPS = 1e-12f, EPSN = 1e-12f / 1024.f;
    int b = bh >> 4, h = bh & 15;
#pragma unroll
    for (int qi = 0; qi < 2; qi++) {
        float inv[4];
#pragma unroll
        for (int r = 0; r < 4; r++) inv[r] = 1.f / (rs[qi][r] + EPS);
#pragma unroll
        for (int n = 0; n < 4; n++) {
            float vs = vsum[bh * 64 + n * 16 + l15];
#pragma unroll
            for (int r = 0; r < 4; r++) {
                int q = qbase + qi * 16 + lg * 4 + r;
                float val = (ctxa[qi][n][r] + EPSN * vs) * inv[r];
                ctx[(size_t)(b * 1024 + q) * 1024 + h * 64 + n * 16 + l15] = f2bf(val);
            }
        }
    }
}

// ----- fp32 fixup GEMM: q,k rows s<16 of each (b,h) exactly from fp32 X,W -----
__global__ __launch_bounds__(256) void k_qkfix(const float* __restrict__ X,
                                               const float* __restrict__ W,
                                               const float* __restrict__ bias,
                                               float* __restrict__ Qf,
                                               float* __restrict__ Kf) {
    __shared__ float Xl[64][17];  // [kk][row], transposed chunk
    int cb = blockIdx.x, b = blockIdx.y, tid = threadIdx.x;
    int col = cb * 128 + (tid & 127);
    int rb = (tid >> 7) * 8;
    float acc[8] = {};
    for (int k0 = 0; k0 < 1024; k0 += 64) {
        __syncthreads();
        for (int i = tid; i < 1024; i += 256) {
            int r = i >> 6, kk = i & 63;
            Xl[kk][r] = X[((size_t)b * 1024 + r) * 1024 + k0 + kk];
        }
        __syncthreads();
        for (int kk = 0; kk < 64; kk++) {
            float wv = W[(size_t)(k0 + kk) * 3072 + col];
#pragma unroll
            for (int j = 0; j < 8; j++) acc[j] += Xl[kk][rb + j] * wv;
        }
    }
    int isK = col >> 10, h = (col >> 6) & 15, dd = col & 63;
    float* dst = isK ? Kf : Qf;
    float bv = bias[col];
#pragma unroll
    for (int j = 0; j < 8; j++)
        dst[((size_t)(b * 16 + h) * 16 + rb + j) * 64 + dd] = acc[j] + bv;
}

// ----- fp32 fixup attention for rows q<16 of each head -----
__global__ __launch_bounds__(256) void k_attnfix(const float* __restrict__ Qf,
                                                 const float* __restrict__ Kf,
                                                 const u16* __restrict__ Vb,
                                                 const float* __restrict__ vsum,
                                                 u16* __restrict__ ctx) {
    __shared__ float ps[16][17];
    __shared__ float dens[16];
    int bh = blockIdx.x, t = threadIdx.x;
    int q = t >> 4, k = t & 15;
    const float* Qr = Qf + ((size_t)bh * 16 + q) * 64;
    const float* Kr = Kf + ((size_t)bh * 16 + k) * 64;
    float s = 0.f;
    for (int d = 0; d < 64; d++) s += Qr[d] * Kr[d];
    s *= 0.125f;
    float p = (k <= q) ? fmaxf(s, 0.f) : 0.f;
    float den = p;
    den += __shfl_xor(den, 1); den += __shfl_xor(den, 2);
    den += __shfl_xor(den, 4); den += __shfl_xor(den, 8);
    ps[q][k] = p;
    if (k == 0) dens[q] = den;
    __syncthreads();
    int d0 = (t & 15) * 4;
    float c[4] = {};
    for (int kk = 0; kk <= q; kk++) {
        float pv = ps[q][kk];
        const u16* vr = Vb + ((size_t)bh * 1024 + kk) * 64 + d0;
        c[0] += pv * bf2f(vr[0]); c[1] += pv * bf2f(vr[1]);
        c[2] += pv * bf2f(vr[2]); c[3] += pv * bf2f(vr[3]);
    }
    float inv = 1.f / (dens[q] + 1e-12f);
    const float EPSN = 1e-12f / 1024.f;
    const float* vs = vsum + bh * 64 + d0;
    int b = bh >> 4, h = bh & 15;
    u16* dst = ctx + (size_t)(b * 1024 + q) * 1024 + h * 64 + d0;
#pragma unroll
    for (int j = 0; j < 4; j++) dst[j] = f2bf((c[j] + EPSN * vs[j]) * inv);
}

extern "C" void kernel_launch(void* const* d_in, const int* in_sizes, int n_in,
                              void* d_out, int out_size, void* d_ws, size_t ws_size,
                              hipStream_t stream) {
    const float* X = (const float*)d_in[0];
    const float* Wqkv = (const float*)d_in[1];
    const float* bqkv = (const float*)d_in[2];
    const float* Wproj = (const float*)d_in[3];
    const float* bproj = (const float*)d_in[4];
    float* out = (float*)d_out;
    char* ws = (char*)d_ws;

    u16* Xb     = (u16*)(ws);                       // 8.4 MB (reused as ctx)
    u16* Wqkvt  = (u16*)(ws + 8388608);             // 6.3 MB
    u16* Wprojt = (u16*)(ws + 14680064);            // 2.1 MB
    u16* Qb     = (u16*)(ws + 16777216);            // 8.4 MB
    u16* Kb     = (u16*)(ws + 25165824);            // 8.4 MB
    u16* Vb     = (u16*)(ws + 33554432);            // 8.4 MB
    u16* Vt     = (u16*)(ws + 41943040);            // 8.4 MB
    float* vsum = (float*)(ws + 50331648);          // 16 KB
    float* Qf   = (float*)(ws + 50348032);          // 256 KB
    float* Kf   = (float*)(ws + 50610176);          // 256 KB
    u16* ctx    = Xb;  // Xb dead after GEMM1; reuse for ctx

    k_cast_bf16<<<dim3(2048), dim3(256), 0, stream>>>(X, Xb, 524288);
    k_wtrans<<<dim3(48, 16), dim3(256), 0, stream>>>(Wqkv, Wqkvt, 1024, 3072);
    k_wtrans<<<dim3(16, 16), dim3(256), 0, stream>>>(Wproj, Wprojt, 1024, 1024);
    k_gemm<1><<<dim3(32, 24), dim3(256), 0, stream>>>(Xb, Wqkvt, bqkv, nullptr,
                                                      Qb, Kb, Vb, 4096, 3072, 1024);
    k_vtrans<<<dim3(16, 64), dim3(256), 0, stream>>>(Vb, Vt);
    k_vsum<<<dim3(64), dim3(256), 0, stream>>>(Vb, vsum);
    k_qkfix<<<dim3(16, 4), dim3(256), 0, stream>>>(X, Wqkv, bqkv, Qf, Kf);
    k_attn<<<dim3(8, 64), dim3(256), 0, stream>>>(Qb, Kb, Vt, vsum, ctx);
    k_attnfix<<<dim3(64), dim3(256), 0, stream>>>(Qf, Kf, Vb, vsum, ctx);
    k_gemm<0><<<dim3(32, 8), dim3(256), 0, stream>>>(ctx, Wprojt, bproj, out,
                                                     nullptr, nullptr, nullptr, 4096, 1024, 1024);
}

// Round 2
// 231.021 us; speedup vs baseline: 1.2233x; 1.2233x over previous
//
#include <hip/hip_runtime.h>
#include <hip/hip_bf16.h>

typedef unsigned short u16;
typedef unsigned int u32;

#define AS1 __attribute__((address_space(1)))
#define AS3 __attribute__((address_space(3)))

typedef __attribute__((ext_vector_type(8))) __bf16 bf16x8;
typedef __attribute__((ext_vector_type(4))) float f32x4;
typedef __attribute__((ext_vector_type(8))) u16 u16x8;

static __device__ __forceinline__ u16 f2bf(float f) {
    u32 x = __builtin_bit_cast(u32, f);
    u32 r = (x + 0x7fffu + ((x >> 16) & 1u)) >> 16;
    return (u16)r;
}
static __device__ __forceinline__ float bf2f(u16 u) {
    u32 x = ((u32)u) << 16;
    return __builtin_bit_cast(float, x);
}
static __device__ __forceinline__ void gload_lds16(const void* g, void* l) {
    __builtin_amdgcn_global_load_lds((const AS1 u32*)g, (AS3 u32*)l, 16, 0, 0);
}

// ---------------- cast X (fp32 -> bf16), 8 elems/thread ----------------
__global__ __launch_bounds__(256) void k_cast_bf16(const float* __restrict__ in,
                                                   u16* __restrict__ out, int n8) {
    int i = blockIdx.x * 256 + threadIdx.x;
    if (i >= n8) return;
    typedef __attribute__((ext_vector_type(4))) float fx4;
    const fx4* p = (const fx4*)in;
    fx4 a = p[2 * i], b = p[2 * i + 1];
    u16x8 o;
    o[0] = f2bf(a[0]); o[1] = f2bf(a[1]); o[2] = f2bf(a[2]); o[3] = f2bf(a[3]);
    o[4] = f2bf(b[0]); o[5] = f2bf(b[1]); o[6] = f2bf(b[2]); o[7] = f2bf(b[3]);
    *(u16x8*)(out + (size_t)i * 8) = o;
}

// ------------- transpose + cast W: [K,N] fp32 -> [N,K] bf16 -------------
__global__ __launch_bounds__(256) void k_wtrans(const float* __restrict__ W,
                                                u16* __restrict__ Wt, int K_, int N_) {
    __shared__ u16 T[64][65];
    int nt = blockIdx.x, kt = blockIdx.y;
    int t = threadIdx.x, c = t & 63, r0 = t >> 6;
#pragma unroll
    for (int i = 0; i < 16; i++) {
        int k = r0 + i * 4;
        T[k][c] = f2bf(W[(size_t)(kt * 64 + k) * N_ + nt * 64 + c]);
    }
    __syncthreads();
#pragma unroll
    for (int i = 0; i < 16; i++) {
        int nn = r0 + i * 4;
        Wt[(size_t)(nt * 64 + nn) * K_ + kt * 64 + c] = T[c][nn];
    }
}

// ---------------- bf16 MFMA GEMM: A[M,K] x Bt[N,K]^T ----------------
// EPI=0: outf[M,N] fp32 + bias.  EPI=1: scatter to Q/K/V bf16 [B,H,S,dh] + bias.
template <int EPI>
__global__ __launch_bounds__(256, 2) void k_gemm(
    const u16* __restrict__ A, const u16* __restrict__ Bt,
    const float* __restrict__ bias, float* __restrict__ outf,
    u16* __restrict__ Qb, u16* __restrict__ Kb, u16* __restrict__ Vb,
    int Msz, int Nsz, int Ksz) {
    __shared__ u16 Al[128 * 64];
    __shared__ u16 Bl[128 * 64];
    int tid = threadIdx.x;
    int m0 = blockIdx.x * 128, n0 = blockIdx.y * 128;
    int w = tid >> 6, lane = tid & 63, l15 = lane & 15, lg = lane >> 4;
    int wr = (w >> 1) * 64, wc = (w & 1) * 64;
    f32x4 acc[4][4] = {};

    for (int k0 = 0; k0 < Ksz; k0 += 64) {
#pragma unroll
        for (int i = 0; i < 4; i++) {
            int c = i * 256 + tid;
            gload_lds16(A + (size_t)(m0 + (c >> 3)) * Ksz + k0 + (c & 7) * 8,
                        &Al[(c & ~63) * 8]);
        }
#pragma unroll
        for (int i = 0; i < 4; i++) {
            int c = i * 256 + tid;
            gload_lds16(Bt + (size_t)(n0 + (c >> 3)) * Ksz + k0 + (c & 7) * 8,
                        &Bl[(c & ~63) * 8]);
        }
        __syncthreads();
#pragma unroll
        for (int kk = 0; kk < 2; kk++) {
            bf16x8 af[4], bfr[4];
#pragma unroll
            for (int m = 0; m < 4; m++)
                af[m] = *(const bf16x8*)&Al[(wr + m * 16 + l15) * 64 + kk * 32 + lg * 8];
#pragma unroll
            for (int n = 0; n < 4; n++)
                bfr[n] = *(const bf16x8*)&Bl[(wc + n * 16 + l15) * 64 + kk * 32 + lg * 8];
#pragma unroll
            for (int m = 0; m < 4; m++)
#pragma unroll
                for (int n = 0; n < 4; n++)
                    acc[m][n] = __builtin_amdgcn_mfma_f32_16x16x32_bf16(af[m], bfr[n], acc[m][n], 0, 0, 0);
        }
        __syncthreads();
    }

    if (EPI == 0) {
#pragma unroll
        for (int n = 0; n < 4; n++) {
            int gn = n0 + wc + n * 16 + l15;
            float bv = bias[gn];
#pragma unroll
            for (int m = 0; m < 4; m++) {
                int gmb = m0 + wr + m * 16 + lg * 4;
#pragma unroll
                for (int r = 0; r < 4; r++)
                    outf[(size_t)(gmb + r) * Nsz + gn] = acc[m][n][r] + bv;
            }
        }
    } else {
#pragma unroll
        for (int n = 0; n < 4; n++) {
            int gn = n0 + wc + n * 16 + l15;
            float bv = bias[gn];
            int which = gn >> 10, d = gn & 1023, h = d >> 6, dd = d & 63;
            u16* dst = which == 0 ? Qb : (which == 1 ? Kb : Vb);
#pragma unroll
            for (int m = 0; m < 4; m++) {
                int gmb = m0 + wr + m * 16 + lg * 4;
#pragma unroll
                for (int r = 0; r < 4; r++) {
                    int gm = gmb + r;
                    int b = gm >> 10, s = gm & 1023;
                    dst[((size_t)(b * 16 + h) * 1024 + s) * 64 + dd] = f2bf(acc[m][n][r] + bv);
                }
            }
        }
    }
}

// ---------------- V transpose: [bh][S][64] -> [bh][64][S] ----------------
__global__ __launch_bounds__(256) void k_vtrans(const u16* __restrict__ Vb,
                                                u16* __restrict__ Vt) {
    __shared__ u16 T[64][65];
    int st = blockIdx.x, bh = blockIdx.y;
    int t = threadIdx.x, c = t & 63, r0 = t >> 6;
    const u16* Vh = Vb + (size_t)bh * 65536;
    u16* Vth = Vt + (size_t)bh * 65536;
#pragma unroll
    for (int i = 0; i < 16; i++) {
        int s = r0 + i * 4;
        T[s][c] = Vh[(size_t)(st * 64 + s) * 64 + c];
    }
    __syncthreads();
#pragma unroll
    for (int i = 0; i < 16; i++) {
        int d = r0 + i * 4;
        Vth[(size_t)d * 1024 + st * 64 + c] = T[c][d];
    }
}

// ---------------- vsum: per (bh,d) sum over s of V ----------------
__global__ __launch_bounds__(256) void k_vsum(const u16* __restrict__ Vb,
                                              float* __restrict__ vsum) {
    __shared__ float red[256];
    int bh = blockIdx.x, t = threadIdx.x;
    int d = t & 63, sr = t >> 6;
    const u16* Vh = Vb + (size_t)bh * 65536;
    float a = 0.f;
    for (int s = sr; s < 1024; s += 4) a += bf2f(Vh[(size_t)s * 64 + d]);
    red[t] = a;
    __syncthreads();
    if (t < 64) vsum[bh * 64 + t] = red[t] + red[t + 64] + red[t + 128] + red[t + 192];
}

// ---------------- attention: relu-softmax flash, bf16 MFMA ----------------
__global__ __launch_bounds__(256) void k_attn(const u16* __restrict__ Qb,
                                              const u16* __restrict__ Kb,
                                              const u16* __restrict__ Vt,
                                              const float* __restrict__ vsum,
                                              u16* __restrict__ ctx) {
    __shared__ u16 Pl[4 * 2048];
    int qt = blockIdx.x, bh = blockIdx.y;
    int tid = threadIdx.x, w = tid >> 6, lane = tid & 63, l15 = lane & 15, lg = lane >> 4;
    const u16* Qh = Qb + (size_t)bh * 65536;
    const u16* Kh = Kb + (size_t)bh * 65536;
    const u16* Vh = Vt + (size_t)bh * 65536;
    int qbase = qt * 128 + w * 32;
    u16* Pw = &Pl[w * 2048];

    bf16x8 qf[2][2];
#pragma unroll
    for (int qi = 0; qi < 2; qi++)
#pragma unroll
        for (int kk = 0; kk < 2; kk++)
            qf[qi][kk] = *(const bf16x8*)(Qh + (size_t)(qbase + qi * 16 + l15) * 64 + kk * 32 + lg * 8);

    f32x4 ctxa[2][4] = {};
    float rs[2][4] = {};
    int nkb = (qbase + 95) >> 6;
    for (int kb = 0; kb < nkb; kb++) {
        f32x4 sc[2][4] = {};
#pragma unroll
        for (int kk = 0; kk < 2; kk++) {
            bf16x8 kf[4];
#pragma unroll
            for (int n = 0; n < 4; n++)
                kf[n] = *(const bf16x8*)(Kh + (size_t)(kb * 64 + n * 16 + l15) * 64 + kk * 32 + lg * 8);
#pragma unroll
            for (int qi = 0; qi < 2; qi++)
#pragma unroll
                for (int n = 0; n < 4; n++)
                    sc[qi][n] = __builtin_amdgcn_mfma_f32_16x16x32_bf16(qf[qi][kk], kf[n], sc[qi][n], 0, 0, 0);
        }
#pragma unroll
        for (int qi = 0; qi < 2; qi++)
#pragma unroll
            for (int n = 0; n < 4; n++)
#pragma unroll
                for (int r = 0; r < 4; r++) {
                    int qrow = qi * 16 + lg * 4 + r;
                    int q = qbase + qrow;
                    int k = kb * 64 + n * 16 + l15;
                    float p = sc[qi][n][r] * 0.125f;
                    p = (k <= q) ? fmaxf(p, 0.f) : 0.f;
                    rs[qi][r] += p;
                    int byte = qrow * 128 + (n * 16 + l15) * 2;
                    byte ^= (qrow & 7) << 4;  // XOR-swizzle (G4)
                    Pw[byte >> 1] = f2bf(p);
                }
#pragma unroll
        for (int kk = 0; kk < 2; kk++) {
            bf16x8 pf[2], vf[4];
#pragma unroll
            for (int qi = 0; qi < 2; qi++) {
                int row = qi * 16 + l15;
                int byte = row * 128 + (kk * 32 + lg * 8) * 2;
                byte ^= (row & 7) << 4;
                pf[qi] = *(const bf16x8*)&Pw[byte >> 1];
            }
#pragma unroll
            for (int n = 0; n < 4; n++)
                vf[n] = *(const bf16x8*)(Vh + (size_t)(n * 16 + l15) * 1024 + kb * 64 + kk * 32 + lg * 8);
#pragma unroll
            for (int qi = 0; qi < 2; qi++)
#pragma unroll
                for (int n = 0; n < 4; n++)
                    ctxa[qi][n] = __builtin_amdgcn_mfma_f32_16x16x32_bf16(pf[qi], vf[n], ctxa[qi][n], 0, 0, 0);
        }
    }
#pragma unroll
    for (int qi = 0; qi < 2; qi++)
#pragma unroll
        for (int r = 0; r < 4; r++) {
            float t = rs[qi][r];
            t += __shfl_xor(t, 1); t += __shfl_xor(t, 2);
            t += __shfl_xor(t, 4); t += __shfl_xor(t, 8);
            rs[qi][r] = t;
        }
    const float EPS = 1e-12f, EPSN = 1e-12f / 1024.f;
    int b = bh >> 4, h = bh & 15;
#pragma unroll
    for (int qi = 0; qi < 2; qi++) {
        float inv[4];
#pragma unroll
        for (int r = 0; r < 4; r++) inv[r] = 1.f / (rs[qi][r] + EPS);
#pragma unroll
        for (int n = 0; n < 4; n++) {
            float vs = vsum[bh * 64 + n * 16 + l15];
#pragma unroll
            for (int r = 0; r < 4; r++) {
                int q = qbase + qi * 16 + lg * 4 + r;
                float val = (ctxa[qi][n][r] + EPSN * vs) * inv[r];
                ctx[(size_t)(b * 1024 + q) * 1024 + h * 64 + n * 16 + l15] = f2bf(val);
            }
        }
    }
}

// ----- fp32 fixup GEMM: q,k rows s<16 of each (b,h) exactly from fp32 X,W -----
// K-split across 4 waves; LDS reduce. grid (32 colblocks, 8 = b*2+rowhalf).
__global__ __launch_bounds__(256) void k_qkfix(const float* __restrict__ X,
                                               const float* __restrict__ W,
                                               const float* __restrict__ bias,
                                               float* __restrict__ Qf,
                                               float* __restrict__ Kf) {
    __shared__ float red[4][8][64];
    int cb = blockIdx.x;          // 64-col block: cb<16 -> Q, cb>=16 -> K
    int b = blockIdx.y >> 1, rh = blockIdx.y & 1;
    int tid = threadIdx.x, w = tid >> 6, lane = tid & 63;
    int col = cb * 64 + lane;

    const float* Wp = W + (size_t)(w * 256) * 3072 + col;
    const float* Xp = X + ((size_t)b * 1024 + rh * 8) * 1024 + w * 256;
    float acc[8] = {};
#pragma unroll 8
    for (int it = 0; it < 256; ++it) {
        float wv = Wp[(size_t)it * 3072];
#pragma unroll
        for (int j = 0; j < 8; j++) acc[j] += Xp[(size_t)j * 1024 + it] * wv;
    }
#pragma unroll
    for (int j = 0; j < 8; j++) red[w][j][lane] = acc[j];
    __syncthreads();

    int isK = cb >> 4, h = cb & 15;
    float* dst = isK ? Kf : Qf;
#pragma unroll
    for (int o = tid; o < 512; o += 256) {
        int j = o >> 6, c = o & 63;
        float s = red[0][j][c] + red[1][j][c] + red[2][j][c] + red[3][j][c];
        dst[((size_t)(b * 16 + h) * 16 + rh * 8 + j) * 64 + c] = s + bias[cb * 64 + c];
    }
}

// ----- fp32 fixup attention for rows q<16 of each head -----
__global__ __launch_bounds__(256) void k_attnfix(const float* __restrict__ Qf,
                                                 const float* __restrict__ Kf,
                                                 const u16* __restrict__ Vb,
                                                 const float* __restrict__ vsum,
                                                 u16* __restrict__ ctx) {
    __shared__ float ps[16][17];
    __shared__ float dens[16];
    int bh = blockIdx.x, t = threadIdx.x;
    int q = t >> 4, k = t & 15;
    const float* Qr = Qf + ((size_t)bh * 16 + q) * 64;
    const float* Kr = Kf + ((size_t)bh * 16 + k) * 64;
    float s = 0.f;
    for (int d = 0; d < 64; d++) s += Qr[d] * Kr[d];
    s *= 0.125f;
    float p = (k <= q) ? fmaxf(s, 0.f) : 0.f;
    float den = p;
    den += __shfl_xor(den, 1); den += __shfl_xor(den, 2);
    den += __shfl_xor(den, 4); den += __shfl_xor(den, 8);
    ps[q][k] = p;
    if (k == 0) dens[q] = den;
    __syncthreads();
    int d0 = (t & 15) * 4;
    float c[4] = {};
    for (int kk = 0; kk <= q; kk++) {
        float pv = ps[q][kk];
        const u16* vr = Vb + ((size_t)bh * 1024 + kk) * 64 + d0;
        c[0] += pv * bf2f(vr[0]); c[1] += pv * bf2f(vr[1]);
        c[2] += pv * bf2f(vr[2]); c[3] += pv * bf2f(vr[3]);
    }
    float inv = 1.f / (dens[q] + 1e-12f);
    const float EPSN = 1e-12f / 1024.f;
    const float* vs = vsum + bh * 64 + d0;
    int b = bh >> 4, h = bh & 15;
    u16* dst = ctx + (size_t)(b * 1024 + q) * 1024 + h * 64 + d0;
#pragma unroll
    for (int j = 0; j < 4; j++) dst[j] = f2bf((c[j] + EPSN * vs[j]) * inv);
}

extern "C" void kernel_launch(void* const* d_in, const int* in_sizes, int n_in,
                              void* d_out, int out_size, void* d_ws, size_t ws_size,
                              hipStream_t stream) {
    const float* X = (const float*)d_in[0];
    const float* Wqkv = (const float*)d_in[1];
    const float* bqkv = (const float*)d_in[2];
    const float* Wproj = (const float*)d_in[3];
    const float* bproj = (const float*)d_in[4];
    float* out = (float*)d_out;
    char* ws = (char*)d_ws;

    u16* Xb     = (u16*)(ws);                       // 8.4 MB (reused as ctx)
    u16* Wqkvt  = (u16*)(ws + 8388608);             // 6.3 MB
    u16* Wprojt = (u16*)(ws + 14680064);            // 2.1 MB
    u16* Qb     = (u16*)(ws + 16777216);            // 8.4 MB
    u16* Kb     = (u16*)(ws + 25165824);            // 8.4 MB
    u16* Vb     = (u16*)(ws + 33554432);            // 8.4 MB
    u16* Vt     = (u16*)(ws + 41943040);            // 8.4 MB
    float* vsum = (float*)(ws + 50331648);          // 16 KB
    float* Qf   = (float*)(ws + 50348032);          // 256 KB
    float* Kf   = (float*)(ws + 50610176);          // 256 KB
    u16* ctx    = Xb;  // Xb dead after GEMM1; reuse for ctx

    k_cast_bf16<<<dim3(2048), dim3(256), 0, stream>>>(X, Xb, 524288);
    k_wtrans<<<dim3(48, 16), dim3(256), 0, stream>>>(Wqkv, Wqkvt, 1024, 3072);
    k_wtrans<<<dim3(16, 16), dim3(256), 0, stream>>>(Wproj, Wprojt, 1024, 1024);
    k_gemm<1><<<dim3(32, 24), dim3(256), 0, stream>>>(Xb, Wqkvt, bqkv, nullptr,
                                                      Qb, Kb, Vb, 4096, 3072, 1024);
    k_vtrans<<<dim3(16, 64), dim3(256), 0, stream>>>(Vb, Vt);
    k_vsum<<<dim3(64), dim3(256), 0, stream>>>(Vb, vsum);
    k_qkfix<<<dim3(32, 8), dim3(256), 0, stream>>>(X, Wqkv, bqkv, Qf, Kf);
    k_attn<<<dim3(8, 64), dim3(256), 0, stream>>>(Qb, Kb, Vt, vsum, ctx);
    k_attnfix<<<dim3(64), dim3(256), 0, stream>>>(Qf, Kf, Vb, vsum, ctx);
    k_gemm<0><<<dim3(32, 8), dim3(256), 0, stream>>>(ctx, Wprojt, bproj, out,
                                                     nullptr, nullptr, nullptr, 4096, 1024, 1024);
}